// Round 1
// 1086.852 us; speedup vs baseline: 1.0689x; 1.0689x over previous
//
#include <hip/hip_runtime.h>
#include <float.h>
#include <math.h>

#define TOKENS 16384
#define DIM    7168
#define NEXP   256
#define BM     64
#define BK     32
#define NCHUNK (DIM / BK)   // 224
#define NGROUP (NCHUNK / 4) // 56 groups of 4 chunks
#define ROUTE_SCALE 2.5
#define TAU      6e-6f      // ~50x rms score error of the fp16-split path
#define WSCALE   1024.0f    // lifts W_lo out of fp16 denormal range (exact pow2)
#define WUNSCALE 0.0009765625f

typedef _Float16 half8  __attribute__((ext_vector_type(8)));
typedef _Float16 half4v __attribute__((ext_vector_type(4)));
typedef float    f32x4  __attribute__((ext_vector_type(4)));

#define WPLANE 1835008      // 256*7168 halves per plane

__device__ __forceinline__ _Float16 hi16(float f) { return (_Float16)f; }
__device__ __forceinline__ _Float16 lo16(float f) {
    _Float16 h = (_Float16)f;
    return (_Float16)(f - (float)h);
}

// ---------------- Kernel 0: split (W*1024) into fp16 hi/lo planes, CHUNK-MAJOR ----------------
// Layout: plane[(k>>5)*8192 + e*32 + (k&31)] -> per K-chunk, all 256 experts contiguous.
// A wave's B-fragment load (16 experts x 64 B) is then a contiguous 1 KB stream.
__global__ __launch_bounds__(256)
void conv_w(const float* __restrict__ W, _Float16* __restrict__ Wh, _Float16* __restrict__ Wl) {
    int i = blockIdx.x * 256 + threadIdx.x;       // over 458752 float4s (exact)
    int f = i * 4;
    int e = f / DIM;
    int k = f - e * DIM;
    float4 v = ((const float4*)W)[i];
    v.x *= WSCALE; v.y *= WSCALE; v.z *= WSCALE; v.w *= WSCALE;
    half4v h, l;
    h[0] = hi16(v.x); l[0] = lo16(v.x);
    h[1] = hi16(v.y); l[1] = lo16(v.y);
    h[2] = hi16(v.z); l[2] = lo16(v.z);
    h[3] = hi16(v.w); l[3] = lo16(v.w);
    int o = ((k >> 5) << 13) + (e << 5) + (k & 31);   // chunk-major offset
    *(half4v*)(Wh + o) = h;
    *(half4v*)(Wl + o) = l;
}

// ---------------- Kernel 1: fp16-split MFMA GEMM + routing + flags ----------------
// 1024 threads (16 waves), [64 tokens] x [256 experts] per block, grid 256 (1 block/CU, 4 waves/SIMD).
// Wave wid: mh=wid>>3 (token half, 32 rows), ns=wid&7 (expert slice, 32 cols); tile 2m x 2n of 16x16.
// X staged in LDS (fp16 hi/lo, converted ONCE) in groups of 4 chunks, double-buffered:
//   one __syncthreads per GROUP (57 barriers total vs 226 before).
// W streams global->regs (chunk-major, contiguous 1 KB/wave-load), 1-chunk prefetch, barrier-free.
// LDS X tile XOR-swizzled on 16B granules: slot ^= (row>>1)&3  (64B rows -> 2-way instead of 8-way).
// Per-(t,e) product set/order and accf dump cadence identical to previous verified kernel
// -> logits bit-identical -> TAU margins and gate_fix behavior unchanged.
__global__ __launch_bounds__(1024, 4)
void gate_main(const float* __restrict__ X, const _Float16* __restrict__ Wh,
               const _Float16* __restrict__ Wl, const float* __restrict__ Bp,
               float* __restrict__ outw, float* __restrict__ outi,
               unsigned char* __restrict__ flags) {
    __shared__ float smem[16384];                 // 64 KB: X dbuf (2 x 32 KB); routing overlay after
    _Float16* hb = (_Float16*)smem;

    const int tid  = threadIdx.x;
    const int lane = tid & 63;
    const int wid  = tid >> 6;                    // 0..15
    const int mh   = wid >> 3;                    // 0..1  (token half: 32 rows)
    const int ns   = wid & 7;                     // 0..7  (expert slice: 32 cols)
    const int m0   = blockIdx.x * BM;
    const int fr   = lane & 15;
    const int fk   = lane >> 4;                   // 0..3

    // X staging map: thread -> (chunk-in-group, row, 16B slot)
    const int xcc = tid >> 8;                     // 0..3
    const int xr  = (tid >> 2) & 63;              // 0..63
    const int xs  = tid & 3;                      // 0..3
    const float* xsrc = X + (size_t)(m0 + xr) * DIM + xcc * 32 + xs * 8;
    const int xdst = xcc * 4096 + xr * 32 + ((xs ^ ((xr >> 1) & 3)) << 3);

    // A-fragment LDS base (halves), constant per lane per m-tile (swizzled)
    int abase[2];
    #pragma unroll
    for (int m = 0; m < 2; ++m) {
        const int row = mh * 32 + m * 16 + fr;
        abase[m] = row * 32 + ((fk ^ ((row >> 1) & 3)) << 3);
    }

    // W chunk-major per-lane pointers; chunk c lives at +c*8192 halves
    const int wro = ((ns * 32 + fr) << 5) + fk * 8;
    const _Float16* wph0 = Wh + wro;
    const _Float16* wph1 = Wh + wro + 512;        // n=1: +16 experts * 32 halves
    const _Float16* wpl0 = Wl + wro;
    const _Float16* wpl1 = Wl + wro + 512;

    f32x4 acc[2][2]  = {};
    f32x4 accf[2][2] = {};
    half8 bh[2][2], bl[2][2];                     // [reg set][n]
    float4 xa, xb;

    // ---- prologue: stage X group 0 into buf0; load W chunk 0 into set 0 ----
    {
        xa = *(const float4*)(xsrc);
        xb = *(const float4*)(xsrc + 4);
        half8 h8, l8;
        const float v[8] = {xa.x, xa.y, xa.z, xa.w, xb.x, xb.y, xb.z, xb.w};
        #pragma unroll
        for (int e = 0; e < 8; ++e) { h8[e] = hi16(v[e]); l8[e] = lo16(v[e]); }
        *(half8*)(hb + xdst)        = h8;
        *(half8*)(hb + xdst + 2048) = l8;
    }
    bh[0][0] = *(const half8*)(wph0);
    bh[0][1] = *(const half8*)(wph1);
    bl[0][0] = *(const half8*)(wpl0);
    bl[0][1] = *(const half8*)(wpl1);
    __syncthreads();

    for (int g = 0; g < NGROUP; ++g) {
        const int p = g & 1;
        if (g + 1 < NGROUP) {                     // prefetch next X group into regs (4 chunks of cover)
            const float* src = xsrc + (size_t)(g + 1) * 128;
            xa = *(const float4*)(src);
            xb = *(const float4*)(src + 4);
        }
        #pragma unroll
        for (int cc = 0; cc < 4; ++cc) {
            const int c = g * 4 + cc;
            const int s = cc & 1;
            if (c + 1 < NCHUNK) {                 // prefetch next W chunk into other reg set
                const size_t co = (size_t)(c + 1) * 8192;
                bh[s ^ 1][0] = *(const half8*)(wph0 + co);
                bh[s ^ 1][1] = *(const half8*)(wph1 + co);
                bl[s ^ 1][0] = *(const half8*)(wpl0 + co);
                bl[s ^ 1][1] = *(const half8*)(wpl1 + co);
            }
            const _Float16* ab = hb + p * 16384 + cc * 4096;
            half8 ah[2], al[2];
            ah[0] = *(const half8*)(ab + abase[0]);
            ah[1] = *(const half8*)(ab + abase[1]);
            al[0] = *(const half8*)(ab + 2048 + abase[0]);
            al[1] = *(const half8*)(ab + 2048 + abase[1]);
            #pragma unroll
            for (int m = 0; m < 2; ++m)
                #pragma unroll
                for (int n = 0; n < 2; ++n) {
                    acc[m][n] = __builtin_amdgcn_mfma_f32_16x16x32_f16(ah[m], bh[s][n], acc[m][n], 0, 0, 0);
                    acc[m][n] = __builtin_amdgcn_mfma_f32_16x16x32_f16(ah[m], bl[s][n], acc[m][n], 0, 0, 0);
                    acc[m][n] = __builtin_amdgcn_mfma_f32_16x16x32_f16(al[m], bh[s][n], acc[m][n], 0, 0, 0);
                }
            if (cc == 3 && (g & 3) == 3) {        // fp32 master dump every 16 chunks (same cadence)
                #pragma unroll
                for (int m = 0; m < 2; ++m)
                    #pragma unroll
                    for (int n = 0; n < 2; ++n) {
                        accf[m][n] += acc[m][n];
                        acc[m][n] = (f32x4)(0.0f);
                    }
            }
        }
        if (g + 1 < NGROUP) {                     // convert + write next group's X into other buffer
            half8 h8, l8;
            const float v[8] = {xa.x, xa.y, xa.z, xa.w, xb.x, xb.y, xb.z, xb.w};
            #pragma unroll
            for (int e = 0; e < 8; ++e) { h8[e] = hi16(v[e]); l8[e] = lo16(v[e]); }
            _Float16* d = hb + (p ^ 1) * 16384 + xdst;
            *(half8*)(d)        = h8;
            *(half8*)(d + 2048) = l8;
        }
        __syncthreads();                          // one barrier per 4 chunks
    }

    // ---- logits (unscaled) to rotated LDS overlay ----
    float* lg = smem;                             // [64][256], word = t*256 + ((e+t)&255)
    #pragma unroll
    for (int m = 0; m < 2; ++m)
        #pragma unroll
        for (int n = 0; n < 2; ++n)
            #pragma unroll
            for (int r = 0; r < 4; ++r) {
                int t = mh * 32 + m * 16 + fk * 4 + r;   // D row = (lane>>4)*4 + reg
                int e = ns * 32 + n * 16 + fr;           // D col = lane&15
                lg[t * 256 + ((e + t) & 255)] = accf[m][n][r] * WUNSCALE;
            }
    __syncthreads();

    // ---- fp32 routing + margin flags: one thread per token (R4/R7-verified, verbatim) ----
    if (tid < BM) {
        const int t = tid;
        const int gtok = m0 + t;
        float* row = lg + t * 256;

        for (int e = 0; e < 256; ++e) {
            int a = (e + t) & 255;
            row[a] = 1.0f / (1.0f + expf(-row[a]));
        }
        float gs[8];
        #pragma unroll
        for (int g = 0; g < 8; ++g) {
            float m1 = -FLT_MAX, m2 = -FLT_MAX;
            for (int e = g * 32; e < g * 32 + 32; ++e) {
                float v = row[(e + t) & 255] + Bp[e];
                if (v > m1) { m2 = m1; m1 = v; }
                else if (v > m2) { m2 = v; }
            }
            gs[g] = m1 + m2;
        }
        unsigned sel = 0;
        #pragma unroll
        for (int r = 0; r < 4; ++r) {
            float best = -FLT_MAX; int bg = 0;
            #pragma unroll
            for (int g = 0; g < 8; ++g)
                if (!((sel >> g) & 1) && gs[g] > best) { best = gs[g]; bg = g; }
            sel |= 1u << bg;
        }
        float selmin = FLT_MAX, unselmax = -FLT_MAX;
        #pragma unroll
        for (int g = 0; g < 8; ++g) {
            if ((sel >> g) & 1) selmin = fminf(selmin, gs[g]);
            else                unselmax = fmaxf(unselmax, gs[g]);
        }
        bool flag = (selmin - unselmax) < (2.0f * TAU);

        float pv = FLT_MAX; int pe = -1;
        float wv8[8]; int ie8[8]; float wsum = 0.f;
        for (int j = 0; j < 9; ++j) {
            float best = -FLT_MAX; int be = 0;
            for (int e = 0; e < 256; ++e) {
                float v = ((sel >> (e >> 5)) & 1) ? (row[(e + t) & 255] + Bp[e]) : 0.0f;
                bool after = (v < pv) || (v == pv && e > pe);
                if (after && v > best) { best = v; be = e; }
            }
            if (j > 0) flag = flag || ((pv - best) < TAU);
            if (j < 8) {
                float ow = row[(be + t) & 255];
                wv8[j] = ow; ie8[j] = be; wsum += ow;
            }
            pv = best; pe = be;
        }
        flags[gtok] = flag ? 1 : 0;
        float scale = (float)ROUTE_SCALE / wsum;
        #pragma unroll
        for (int j = 0; j < 8; ++j) {
            outw[(size_t)gtok * 8 + j] = wv8[j] * scale;
            outi[(size_t)gtok * 8 + j] = (float)ie8[j];
        }
    }
}

// ---------------- Kernel 2: fp64 recheck of flagged tokens (coalesced, R5/R7-verified) ----------------
__global__ __launch_bounds__(256)
void gate_fix(const float* __restrict__ X, const float* __restrict__ W,
              const float* __restrict__ Bp, float* __restrict__ outw,
              float* __restrict__ outi, const unsigned char* __restrict__ flags) {
    const int t = blockIdx.x;
    if (!flags[t]) return;
    __shared__ float  xrow[DIM];
    __shared__ double sig[NEXP];
    const int tid = threadIdx.x;
    const int s   = tid >> 5;
    const int kt  = tid & 31;

    for (int i = tid * 4; i < DIM; i += 1024)
        *(float4*)(xrow + i) = *(const float4*)(X + (size_t)t * DIM + i);
    __syncthreads();

    for (int i = 0; i < 32; ++i) {
        const int e = i * 8 + s;
        const float* wrow = W + (size_t)e * DIM;
        double s0 = 0, s1 = 0, s2 = 0, s3 = 0;
        for (int c = 0; c < DIM / 128; ++c) {
            int k = c * 128 + kt * 4;
            float4 w4 = *(const float4*)(wrow + k);
            float4 x4 = *(const float4*)(xrow + k);
            s0 = fma((double)x4.x, (double)w4.x, s0);
            s1 = fma((double)x4.y, (double)w4.y, s1);
            s2 = fma((double)x4.z, (double)w4.z, s2);
            s3 = fma((double)x4.w, (double)w4.w, s3);
        }
        double d = (s0 + s1) + (s2 + s3);
        #pragma unroll
        for (int m = 16; m >= 1; m >>= 1)
            d += __shfl_xor(d, m, 32);
        if (kt == 0) sig[e] = 1.0 / (1.0 + exp(-d));
    }
    __syncthreads();

    if (tid == 0) {
        const double* row = sig;
        double gs[8];
        #pragma unroll
        for (int g = 0; g < 8; ++g) {
            double m1 = -DBL_MAX, m2 = -DBL_MAX;
            for (int e = g * 32; e < g * 32 + 32; ++e) {
                double v = row[e] + (double)Bp[e];
                if (v > m1) { m2 = m1; m1 = v; }
                else if (v > m2) { m2 = v; }
            }
            gs[g] = m1 + m2;
        }
        unsigned sel = 0;
        #pragma unroll
        for (int r = 0; r < 4; ++r) {
            double best = -DBL_MAX; int bg = 0;
            #pragma unroll
            for (int g = 0; g < 8; ++g)
                if (!((sel >> g) & 1) && gs[g] > best) { best = gs[g]; bg = g; }
            sel |= 1u << bg;
        }
        double pv = DBL_MAX; int pe = -1;
        double wv8[8]; int ie8[8]; double wsum = 0.0;
        #pragma unroll
        for (int j = 0; j < 8; ++j) {
            double best = -DBL_MAX; int be = 0;
            for (int e = 0; e < 256; ++e) {
                double v = ((sel >> (e >> 5)) & 1) ? (row[e] + (double)Bp[e]) : 0.0;
                bool after = (v < pv) || (v == pv && e > pe);
                if (after && v > best) { best = v; be = e; }
            }
            double ow = row[be];
            wv8[j] = ow; ie8[j] = be; wsum += ow;
            pv = best; pe = be;
        }
        #pragma unroll
        for (int j = 0; j < 8; ++j) {
            outw[(size_t)t * 8 + j] = (float)((wv8[j] / wsum) * ROUTE_SCALE);
            outi[(size_t)t * 8 + j] = (float)ie8[j];
        }
    }
}

extern "C" void kernel_launch(void* const* d_in, const int* in_sizes, int n_in,
                              void* d_out, int out_size, void* d_ws, size_t ws_size,
                              hipStream_t stream) {
    const float* X  = (const float*)d_in[0];
    const float* W  = (const float*)d_in[1];
    const float* Bp = (const float*)d_in[2];
    float* outw = (float*)d_out;
    float* outi = (float*)d_out + (size_t)TOKENS * 8;

    _Float16* Wh = (_Float16*)d_ws;                          // 3.67 MB (chunk-major)
    _Float16* Wl = Wh + WPLANE;                              // 3.67 MB (chunk-major)
    unsigned char* flags = (unsigned char*)(Wl + WPLANE);    // 16 KB

    conv_w   <<<dim3(WPLANE / 1024), dim3(256),  0, stream>>>(W, Wh, Wl);
    gate_main<<<dim3(TOKENS / BM),   dim3(1024), 0, stream>>>(X, Wh, Wl, Bp, outw, outi, flags);
    gate_fix <<<dim3(TOKENS),        dim3(256),  0, stream>>>(X, W, Bp, outw, outi, flags);
}